// Round 1
// baseline (343.877 us; speedup 1.0000x reference)
//
#include <hip/hip_runtime.h>
#include <hip/hip_bf16.h>
#include <math.h>

// ---------------------------------------------------------------------------
// MultiheadSelfAttentionWithRope on MI355X (gfx950), bf16 MFMA pipeline.
// B=4, S=2048, D=1024, H=16, dk=64.  All compute accumulates in fp32.
//
// Stages (all on `stream`):
//   1. convert x + 4 weights fp32 -> bf16           (ws)
//   2. trig table cos/sin [2048][32]                 (ws)
//   3. GEMM<0>: QKV projection (N=3072 fused), epilogue scatters
//      Q,K -> [b,h,s,dk] bf16 and V -> [b,h,dk,s] (pre-transposed for PV)
//   4. RoPE in-place on Q,K (Q also scaled by 1/sqrt(dk)=0.125)
//   5. flash attention -> ab [b,s,h,dk] bf16 (== [M][1024] row-major)
//   6. GEMM<1>: out = ab @ wo.T -> d_out fp32
// ---------------------------------------------------------------------------

typedef __bf16 bf16x8 __attribute__((ext_vector_type(8)));
typedef __bf16 bf16x4 __attribute__((ext_vector_type(4)));
typedef float  f32x4  __attribute__((ext_vector_type(4)));

#define GLB __attribute__((address_space(1)))
#define LDS __attribute__((address_space(3)))

__device__ __forceinline__ void gload_lds16(const void* g, void* l) {
  __builtin_amdgcn_global_load_lds((const GLB unsigned int*)g,
                                   (LDS unsigned int*)l, 16, 0, 0);
}

// ---------------------------------------------------------------------------
// fp32 -> bf16 bulk convert (vectorized float4 -> bf16x4)
// ---------------------------------------------------------------------------
__global__ __launch_bounds__(256) void conv_kernel(const float* __restrict__ in,
                                                   __bf16* __restrict__ out, int n4) {
  int i = blockIdx.x * 256 + threadIdx.x;
  if (i < n4) {
    float4 v = ((const float4*)in)[i];
    bf16x4 o = {(__bf16)v.x, (__bf16)v.y, (__bf16)v.z, (__bf16)v.w};
    ((bf16x4*)out)[i] = o;
  }
}

// ---------------------------------------------------------------------------
// RoPE trig table: trig[s*32+i] = (cos, sin)(pos[s] * 10000^(-i/32))
// ---------------------------------------------------------------------------
__global__ __launch_bounds__(256) void trig_kernel(const int* __restrict__ pos,
                                                   float2* __restrict__ trig) {
  int i = blockIdx.x * 256 + threadIdx.x;  // 65536 total
  int s = i >> 5, fi = i & 31;
  float p = (float)pos[s];
  float freq = expf(-(float)fi * 0.28782313662425574f);  // ln(10000)/32
  float ang = p * freq;
  trig[i] = make_float2(cosf(ang), sinf(ang));
}

// ---------------------------------------------------------------------------
// RoPE in-place on Q ([bh][s][64], also *0.125) and K. One 16B chunk/thread.
// ---------------------------------------------------------------------------
__global__ __launch_bounds__(256) void rope_kernel(__bf16* __restrict__ q,
                                                   __bf16* __restrict__ k,
                                                   const float2* __restrict__ trig) {
  int tid = blockIdx.x * 256 + threadIdx.x;  // 2 * 1048576
  int tensor = tid >> 20;
  int c = tid & 1048575;
  int row = c >> 3;  // bh*2048 + s
  int ch = c & 7;
  int s = row & 2047;
  __bf16* p = (tensor ? k : q) + (size_t)row * 64 + ch * 8;
  bf16x8 v = *(const bf16x8*)p;
  float scale = tensor ? 1.0f : 0.125f;
  bf16x8 o;
#pragma unroll
  for (int t2 = 0; t2 < 4; ++t2) {
    float2 cs = trig[s * 32 + ch * 4 + t2];
    float x0 = (float)v[2 * t2], x1 = (float)v[2 * t2 + 1];
    o[2 * t2]     = (__bf16)((x0 * cs.x - x1 * cs.y) * scale);
    o[2 * t2 + 1] = (__bf16)((x0 * cs.y + x1 * cs.x) * scale);
  }
  *(bf16x8*)p = o;
}

// ---------------------------------------------------------------------------
// 2-phase double-buffered bf16 GEMM, 128x128 tile, BK=64, 4 waves.
// A [M][1024] row-major, B [N][1024] row-major (x@W.T => both K-major).
// LDS tiles [128 rows][64 k] with 16B-chunk XOR swizzle (slot ^= row&7),
// achieved via pre-swizzled per-lane GLOBAL source (linear LDS dest, m173).
// MODE 0: N=3072 (wq|wk|wv), epilogue scatters Q/K ([b,h,s,d]) and V ([b,h,d,s]).
// MODE 1: N=1024 (wo), epilogue writes fp32 d_out.
// ---------------------------------------------------------------------------
template <int MODE>
__global__ __launch_bounds__(256, 2) void gemm_kernel(
    const __bf16* __restrict__ A, const __bf16* __restrict__ Bq,
    const __bf16* __restrict__ Bk, const __bf16* __restrict__ Bv,
    __bf16* __restrict__ Oq, __bf16* __restrict__ Ok, __bf16* __restrict__ Ov,
    float* __restrict__ Of) {
  __shared__ unsigned char sm[65536];  // [A0 16K][B0 16K][A1 16K][B1 16K]
  int bid = blockIdx.x, nwg = gridDim.x;
  int swz = (bid & 7) * (nwg >> 3) + (bid >> 3);  // XCD-aware (nwg % 8 == 0)
  int mt = swz & 63, nt = swz >> 6;
  int m0 = mt * 128;
  const __bf16* Bp;
  int ncol0;
  if (MODE == 0) {
    int sel = nt >> 3;
    Bp = sel == 0 ? Bq : (sel == 1 ? Bk : Bv);
    ncol0 = (nt & 7) * 128;
  } else {
    Bp = Bq;
    ncol0 = nt * 128;
  }
  int t = threadIdx.x;
  int lane = t & 63, w = t >> 6;
  int g = lane >> 4, l15 = lane & 15;
  int wm = w >> 1, wn = w & 1;

  auto stage = [&](int buf, int kt) {
    unsigned boff = (unsigned)buf * 32768u;
#pragma unroll
    for (int l = 0; l < 4; ++l) {
      int c = t + l * 256;
      int r = c >> 3, sl = c & 7;
      int gk = kt * 64 + ((sl ^ (r & 7)) << 3);
      gload_lds16(A + (size_t)(m0 + r) * 1024 + gk, &sm[boff + (unsigned)c * 16]);
    }
#pragma unroll
    for (int l = 0; l < 4; ++l) {
      int c = t + l * 256;
      int r = c >> 3, sl = c & 7;
      int gk = kt * 64 + ((sl ^ (r & 7)) << 3);
      gload_lds16(Bp + (size_t)(ncol0 + r) * 1024 + gk,
                  &sm[boff + 16384u + (unsigned)c * 16]);
    }
  };

  f32x4 acc[4][4] = {};
  stage(0, 0);
  __syncthreads();
  int buf = 0;
  for (int kt = 0; kt < 16; ++kt) {
    if (kt + 1 < 16) stage(buf ^ 1, kt + 1);
    unsigned aoff = (unsigned)buf * 32768u, boff2 = aoff + 16384u;
#pragma unroll
    for (int ks = 0; ks < 2; ++ks) {
      bf16x8 aF[4], bF[4];
      int chunk = ks * 4 + g;
#pragma unroll
      for (int mi = 0; mi < 4; ++mi) {
        int r = wm * 64 + mi * 16 + l15;
        aF[mi] = *(const bf16x8*)&sm[aoff + (unsigned)(r * 128 + ((chunk ^ (r & 7)) << 4))];
      }
#pragma unroll
      for (int ni = 0; ni < 4; ++ni) {
        int r = wn * 64 + ni * 16 + l15;
        bF[ni] = *(const bf16x8*)&sm[boff2 + (unsigned)(r * 128 + ((chunk ^ (r & 7)) << 4))];
      }
#pragma unroll
      for (int mi = 0; mi < 4; ++mi)
#pragma unroll
        for (int ni = 0; ni < 4; ++ni)
          acc[mi][ni] = __builtin_amdgcn_mfma_f32_16x16x32_bf16(aF[mi], bF[ni],
                                                                acc[mi][ni], 0, 0, 0);
    }
    __syncthreads();
    buf ^= 1;
  }
  // epilogue: C row = (lane>>4)*4+j, col = lane&15 (guide-verified layout)
#pragma unroll
  for (int mi = 0; mi < 4; ++mi)
#pragma unroll
    for (int ni = 0; ni < 4; ++ni)
#pragma unroll
      for (int j = 0; j < 4; ++j) {
        int mg = m0 + wm * 64 + mi * 16 + g * 4 + j;
        int col = ncol0 + wn * 64 + ni * 16 + l15;
        float v = acc[mi][ni][j];
        if (MODE == 0) {
          int sel = nt >> 3;
          int h = col >> 6, d = col & 63;
          int b = mg >> 11, s = mg & 2047;
          if (sel == 0)
            Oq[(((size_t)(b * 16 + h)) * 2048 + s) * 64 + d] = (__bf16)v;
          else if (sel == 1)
            Ok[(((size_t)(b * 16 + h)) * 2048 + s) * 64 + d] = (__bf16)v;
          else
            Ov[(((size_t)(b * 16 + h)) * 64 + d) * 2048 + s] = (__bf16)v;  // transposed
        } else {
          Of[(size_t)mg * 1024 + col] = v;
        }
      }
}

// ---------------------------------------------------------------------------
// Flash attention, causal. Grid: bid = qti*64 + bh; qt = 15-qti (heavy first).
// Block: 512 thr (8 waves), each wave owns 16 q-rows of the 128-row q-tile.
// KVBLK=64 double-buffered in LDS (K [64 kv][64 d], V [64 d][64 kv], both
// XOR-swizzled). P goes through per-wave LDS to reach the A-operand layout.
// ---------------------------------------------------------------------------
__global__ __launch_bounds__(512, 4) void attn_kernel(
    const __bf16* __restrict__ Q, const __bf16* __restrict__ Kb,
    const __bf16* __restrict__ Vt, __bf16* __restrict__ Ob) {
  __shared__ unsigned char sm[49152];  // [K0 8K][V0 8K][K1 8K][V1 8K][P 8*2K]
  int bid = blockIdx.x;
  int bh = bid & 63;
  int qt = 15 - (bid >> 6);
  int b = bh >> 4, h = bh & 15;
  const __bf16* Qp = Q + (size_t)bh * 2048 * 64;
  const __bf16* Kp = Kb + (size_t)bh * 2048 * 64;
  const __bf16* Vp = Vt + (size_t)bh * 64 * 2048;
  int t = threadIdx.x;
  int w = t >> 6, lane = t & 63, g = lane >> 4, l15 = lane & 15;
  int qw = qt * 128 + w * 16;

  bf16x8 qF[2];
#pragma unroll
  for (int ks = 0; ks < 2; ++ks)
    qF[ks] = *(const bf16x8*)(Qp + (size_t)(qw + l15) * 64 + ks * 32 + g * 8);

  f32x4 accO[4] = {};
  float mj[4], lj[4];
#pragma unroll
  for (int j = 0; j < 4; ++j) { mj[j] = -1e30f; lj[j] = 0.f; }

  int nsteps = 2 * qt + 2;
  unsigned poff = 32768u + (unsigned)w * 2048u;

  auto stage = [&](int buf, int step) {
    int kv0 = step * 64;
    int r = t >> 3, sl = t & 7;
    gload_lds16(Kp + (size_t)(kv0 + r) * 64 + ((sl ^ (r & 7)) << 3),
                &sm[(unsigned)buf * 16384u + (unsigned)t * 16]);
    gload_lds16(Vp + (size_t)r * 2048 + kv0 + ((sl ^ (r & 7)) << 3),
                &sm[(unsigned)buf * 16384u + 8192u + (unsigned)t * 16]);
  };

  stage(0, 0);
  __syncthreads();
  int buf = 0;
  for (int step = 0; step < nsteps; ++step) {
    if (step + 1 < nsteps) stage(buf ^ 1, step + 1);
    int kv0 = step * 64;
    if (kv0 <= qw + 15) {  // wave-uniform: tile not fully above the diagonal
      unsigned koff = (unsigned)buf * 16384u, voff = koff + 8192u;
      f32x4 sc[4] = {};
#pragma unroll
      for (int ks = 0; ks < 2; ++ks) {
        int chunk = ks * 4 + g;
#pragma unroll
        for (int ntl = 0; ntl < 4; ++ntl) {
          int r = ntl * 16 + l15;
          bf16x8 kf = *(const bf16x8*)&sm[koff + (unsigned)(r * 128 + ((chunk ^ (r & 7)) << 4))];
          sc[ntl] = __builtin_amdgcn_mfma_f32_16x16x32_bf16(qF[ks], kf, sc[ntl], 0, 0, 0);
        }
      }
      if (kv0 + 63 > qw) {  // tile crosses the diagonal for this wave
#pragma unroll
        for (int ntl = 0; ntl < 4; ++ntl)
#pragma unroll
          for (int j = 0; j < 4; ++j) {
            int kvg = kv0 + ntl * 16 + l15;
            int qg = qw + g * 4 + j;
            if (kvg > qg) sc[ntl][j] = -1e30f;
          }
      }
      // online softmax; rows q = qw + g*4 + j live on the 16 lanes of group g
      float alpha[4];
#pragma unroll
      for (int j = 0; j < 4; ++j) {
        float mt_ = fmaxf(fmaxf(sc[0][j], sc[1][j]), fmaxf(sc[2][j], sc[3][j]));
#pragma unroll
        for (int msk = 1; msk < 16; msk <<= 1) mt_ = fmaxf(mt_, __shfl_xor(mt_, msk));
        float mnew = fmaxf(mj[j], mt_);
        alpha[j] = __expf(mj[j] - mnew);
        mj[j] = mnew;
        float ls = 0.f;
#pragma unroll
        for (int ntl = 0; ntl < 4; ++ntl) {
          float p = __expf(sc[ntl][j] - mnew);
          sc[ntl][j] = p;
          ls += p;
        }
#pragma unroll
        for (int msk = 1; msk < 16; msk <<= 1) ls += __shfl_xor(ls, msk);
        lj[j] = lj[j] * alpha[j] + ls;
#pragma unroll
        for (int ntl = 0; ntl < 4; ++ntl) accO[ntl][j] *= alpha[j];
      }
      // P -> per-wave LDS (swizzled), then read back in A-operand layout
#pragma unroll
      for (int ntl = 0; ntl < 4; ++ntl)
#pragma unroll
        for (int j = 0; j < 4; ++j) {
          int ql = g * 4 + j;
          int kv = ntl * 16 + l15;
          unsigned byte = poff + (unsigned)(ql * 128 + ((((kv >> 3) ^ (ql & 7))) << 4) + (kv & 7) * 2);
          *(__bf16*)&sm[byte] = (__bf16)sc[ntl][j];
        }
#pragma unroll
      for (int ks = 0; ks < 2; ++ks) {
        int chunk = ks * 4 + g;
        bf16x8 pf = *(const bf16x8*)&sm[poff + (unsigned)(l15 * 128 + ((chunk ^ (l15 & 7)) << 4))];
#pragma unroll
        for (int ntl = 0; ntl < 4; ++ntl) {
          int r = ntl * 16 + l15;
          bf16x8 vf = *(const bf16x8*)&sm[voff + (unsigned)(r * 128 + ((chunk ^ (r & 7)) << 4))];
          accO[ntl] = __builtin_amdgcn_mfma_f32_16x16x32_bf16(pf, vf, accO[ntl], 0, 0, 0);
        }
      }
    }
    __syncthreads();
    buf ^= 1;
  }
  // epilogue: O /= l, write [b,s,h,d] bf16
#pragma unroll
  for (int j = 0; j < 4; ++j) {
    float inv = 1.0f / lj[j];
    int s = qw + g * 4 + j;
#pragma unroll
    for (int ntl = 0; ntl < 4; ++ntl) {
      int d = ntl * 16 + l15;
      Ob[(((size_t)(b * 2048 + s)) * 16 + h) * 64 + d] = (__bf16)(accO[ntl][j] * inv);
    }
  }
}

// ---------------------------------------------------------------------------
extern "C" void kernel_launch(void* const* d_in, const int* in_sizes, int n_in,
                              void* d_out, int out_size, void* d_ws, size_t ws_size,
                              hipStream_t stream) {
  const float* x  = (const float*)d_in[0];
  const float* wq = (const float*)d_in[1];
  const float* wk = (const float*)d_in[2];
  const float* wv = (const float*)d_in[3];
  const float* wo = (const float*)d_in[4];
  const int* pos  = (const int*)d_in[5];
  float* out = (float*)d_out;

  char* ws = (char*)d_ws;
  size_t off = 0;
  auto alloc = [&](size_t bytes) {
    void* p = ws + off;
    off += (bytes + 255) & ~(size_t)255;
    return p;
  };
  // xb (x in bf16) is dead after the QKV GEMM; reuse its slot for ab.
  __bf16* xb  = (__bf16*)alloc(16777216);   // [8192][1024]
  __bf16* ab  = xb;                          // [8192][1024] ([b,s,h,d])
  __bf16* wqb = (__bf16*)alloc(2097152);
  __bf16* wkb = (__bf16*)alloc(2097152);
  __bf16* wvb = (__bf16*)alloc(2097152);
  __bf16* wob = (__bf16*)alloc(2097152);
  __bf16* qb  = (__bf16*)alloc(16777216);   // [b,h,s,64]
  __bf16* kb  = (__bf16*)alloc(16777216);   // [b,h,s,64]
  __bf16* vt  = (__bf16*)alloc(16777216);   // [b,h,64,s]  (transposed)
  float2* trig = (float2*)alloc(524288);    // [2048][32]
  // total ~72.5 MB of ws

  conv_kernel<<<8192, 256, 0, stream>>>(x, xb, 2097152);
  conv_kernel<<<1024, 256, 0, stream>>>(wq, wqb, 262144);
  conv_kernel<<<1024, 256, 0, stream>>>(wk, wkb, 262144);
  conv_kernel<<<1024, 256, 0, stream>>>(wv, wvb, 262144);
  conv_kernel<<<1024, 256, 0, stream>>>(wo, wob, 262144);
  trig_kernel<<<256, 256, 0, stream>>>(pos, trig);

  gemm_kernel<0><<<1536, 256, 0, stream>>>(xb, wqb, wkb, wvb, qb, kb, vt, nullptr);
  rope_kernel<<<8192, 256, 0, stream>>>(qb, kb, trig);
  attn_kernel<<<1024, 512, 0, stream>>>(qb, kb, vt, ab);
  gemm_kernel<1><<<512, 256, 0, stream>>>(ab, wob, wob, wob, nullptr, nullptr, nullptr, out);
}

// Round 2
// 298.766 us; speedup vs baseline: 1.1510x; 1.1510x over previous
//
#include <hip/hip_runtime.h>
#include <hip/hip_bf16.h>
#include <math.h>

// ---------------------------------------------------------------------------
// MultiheadSelfAttentionWithRope on MI355X (gfx950), bf16 MFMA pipeline.
// B=4, S=2048, D=1024, H=16, dk=64.  fp32 accumulate everywhere.
//
// Stages:
//   1. convert x (+4 weights fused) fp32 -> bf16
//   2. trig table cos/sin [2048][32]
//   3. GEMM<0>: QKV projection (N=3072 fused); epilogue applies RoPE to Q,K
//      (Q also *0.125) and scatters Q,K -> [b,h,s,dk], V -> [b,h,dk,s]
//   4. flash attention (swapped-QK^T, in-register softmax) -> ab [b,s,h,dk]
//   5. GEMM<1>: out = ab @ wo.T -> d_out fp32
// ---------------------------------------------------------------------------

typedef __bf16 bf16x8 __attribute__((ext_vector_type(8)));
typedef __bf16 bf16x4 __attribute__((ext_vector_type(4)));
typedef float  f32x4  __attribute__((ext_vector_type(4)));
typedef float  f32x16 __attribute__((ext_vector_type(16)));

#define GLB __attribute__((address_space(1)))
#define LDS __attribute__((address_space(3)))

__device__ __forceinline__ void gload_lds16(const void* g, void* l) {
  __builtin_amdgcn_global_load_lds((const GLB unsigned int*)g,
                                   (LDS unsigned int*)l, 16, 0, 0);
}

__device__ __forceinline__ unsigned pk2(float a, float b) {
  __bf16 x = (__bf16)a, y = (__bf16)b;
  unsigned short ux = __builtin_bit_cast(unsigned short, x);
  unsigned short uy = __builtin_bit_cast(unsigned short, y);
  return (unsigned)ux | ((unsigned)uy << 16);
}

// ---------------------------------------------------------------------------
// fp32 -> bf16 bulk convert (vectorized float4 -> bf16x4)
// ---------------------------------------------------------------------------
__global__ __launch_bounds__(256) void conv_kernel(const float* __restrict__ in,
                                                   __bf16* __restrict__ out, int n4) {
  int i = blockIdx.x * 256 + threadIdx.x;
  if (i < n4) {
    float4 v = ((const float4*)in)[i];
    bf16x4 o = {(__bf16)v.x, (__bf16)v.y, (__bf16)v.z, (__bf16)v.w};
    ((bf16x4*)out)[i] = o;
  }
}

// 4 weight matrices (each 1M floats) in one launch
__global__ __launch_bounds__(256) void conv4_kernel(
    const float* __restrict__ a, const float* __restrict__ b,
    const float* __restrict__ c, const float* __restrict__ d,
    __bf16* __restrict__ oa, __bf16* __restrict__ ob,
    __bf16* __restrict__ oc, __bf16* __restrict__ od) {
  int i = blockIdx.x * 256 + threadIdx.x;  // 4 * 262144
  int w = i >> 18, j = i & 262143;
  const float* src = w == 0 ? a : (w == 1 ? b : (w == 2 ? c : d));
  __bf16* dst = w == 0 ? oa : (w == 1 ? ob : (w == 2 ? oc : od));
  float4 v = ((const float4*)src)[j];
  bf16x4 o = {(__bf16)v.x, (__bf16)v.y, (__bf16)v.z, (__bf16)v.w};
  ((bf16x4*)dst)[j] = o;
}

// ---------------------------------------------------------------------------
// RoPE trig table: trig[s*32+i] = (cos, sin)(pos[s] * 10000^(-i/32))
// ---------------------------------------------------------------------------
__global__ __launch_bounds__(256) void trig_kernel(const int* __restrict__ pos,
                                                   float2* __restrict__ trig) {
  int i = blockIdx.x * 256 + threadIdx.x;  // 65536 total
  int s = i >> 5, fi = i & 31;
  float p = (float)pos[s];
  float freq = expf(-(float)fi * 0.28782313662425574f);  // ln(10000)/32
  float ang = p * freq;
  trig[i] = make_float2(cosf(ang), sinf(ang));
}

// ---------------------------------------------------------------------------
// 2-phase double-buffered bf16 GEMM, 128x128 tile, BK=64, 4 waves.
// A [M][1024] row-major, B [N][1024] row-major (x@W.T => both K-major).
// LDS tiles [128 rows][64 k], 16B-chunk XOR swizzle via pre-swizzled global src.
// MODE 0: N=3072 (wq|wk|wv); epilogue applies RoPE to Q,K (Q *0.125), scatters
//         Q/K -> [b,h,s,d] and V -> [b,h,d,s].
// MODE 1: N=1024 (wo), epilogue writes fp32 d_out.
// ---------------------------------------------------------------------------
template <int MODE>
__global__ __launch_bounds__(256, 2) void gemm_kernel(
    const __bf16* __restrict__ A, const __bf16* __restrict__ Bq,
    const __bf16* __restrict__ Bk, const __bf16* __restrict__ Bv,
    __bf16* __restrict__ Oq, __bf16* __restrict__ Ok, __bf16* __restrict__ Ov,
    float* __restrict__ Of, const float2* __restrict__ trig) {
  __shared__ unsigned char sm[65536];  // [A0 16K][B0 16K][A1 16K][B1 16K]
  int bid = blockIdx.x, nwg = gridDim.x;
  int swz = (bid & 7) * (nwg >> 3) + (bid >> 3);  // XCD-aware (nwg % 8 == 0)
  int mt = swz & 63, nt = swz >> 6;
  int m0 = mt * 128;
  const __bf16* Bp;
  int ncol0;
  if (MODE == 0) {
    int sel = nt >> 3;
    Bp = sel == 0 ? Bq : (sel == 1 ? Bk : Bv);
    ncol0 = (nt & 7) * 128;
  } else {
    Bp = Bq;
    ncol0 = nt * 128;
  }
  int t = threadIdx.x;
  int lane = t & 63, w = t >> 6;
  int g = lane >> 4, l15 = lane & 15;
  int wm = w >> 1, wn = w & 1;

  auto stage = [&](int buf, int kt) {
    unsigned boff = (unsigned)buf * 32768u;
#pragma unroll
    for (int l = 0; l < 4; ++l) {
      int c = t + l * 256;
      int r = c >> 3, sl = c & 7;
      int gk = kt * 64 + ((sl ^ (r & 7)) << 3);
      gload_lds16(A + (size_t)(m0 + r) * 1024 + gk, &sm[boff + (unsigned)c * 16]);
    }
#pragma unroll
    for (int l = 0; l < 4; ++l) {
      int c = t + l * 256;
      int r = c >> 3, sl = c & 7;
      int gk = kt * 64 + ((sl ^ (r & 7)) << 3);
      gload_lds16(Bp + (size_t)(ncol0 + r) * 1024 + gk,
                  &sm[boff + 16384u + (unsigned)c * 16]);
    }
  };

  f32x4 acc[4][4] = {};
  stage(0, 0);
  __syncthreads();
  int buf = 0;
  for (int kt = 0; kt < 16; ++kt) {
    if (kt + 1 < 16) stage(buf ^ 1, kt + 1);
    unsigned aoff = (unsigned)buf * 32768u, boff2 = aoff + 16384u;
#pragma unroll
    for (int ks = 0; ks < 2; ++ks) {
      bf16x8 aF[4], bF[4];
      int chunk = ks * 4 + g;
#pragma unroll
      for (int mi = 0; mi < 4; ++mi) {
        int r = wm * 64 + mi * 16 + l15;
        aF[mi] = *(const bf16x8*)&sm[aoff + (unsigned)(r * 128 + ((chunk ^ (r & 7)) << 4))];
      }
#pragma unroll
      for (int ni = 0; ni < 4; ++ni) {
        int r = wn * 64 + ni * 16 + l15;
        bF[ni] = *(const bf16x8*)&sm[boff2 + (unsigned)(r * 128 + ((chunk ^ (r & 7)) << 4))];
      }
#pragma unroll
      for (int mi = 0; mi < 4; ++mi)
#pragma unroll
        for (int ni = 0; ni < 4; ++ni)
          acc[mi][ni] = __builtin_amdgcn_mfma_f32_16x16x32_bf16(aF[mi], bF[ni],
                                                                acc[mi][ni], 0, 0, 0);
    }
    __syncthreads();
    buf ^= 1;
  }
  // epilogue: C row = (lane>>4)*4+j, col = lane&15
#pragma unroll
  for (int mi = 0; mi < 4; ++mi)
#pragma unroll
    for (int ni = 0; ni < 4; ++ni)
#pragma unroll
      for (int j = 0; j < 4; ++j) {
        int mg = m0 + wm * 64 + mi * 16 + g * 4 + j;
        int col = ncol0 + wn * 64 + ni * 16 + l15;
        float v = acc[mi][ni][j];
        if (MODE == 0) {
          int sel = nt >> 3;
          int h = col >> 6, d = col & 63;
          int b = mg >> 11, s = mg & 2047;
          if (sel <= 1) {
            // fused RoPE: partner lane holds the other half of the (even,odd) pair
            float p = __shfl_xor(v, 1);
            float2 cs = trig[s * 32 + (d >> 1)];
            float o = (d & 1) ? (p * cs.y + v * cs.x) : (v * cs.x - p * cs.y);
            if (sel == 0) o *= 0.125f;  // 1/sqrt(dk) folded into Q
            if (sel == 0)
              Oq[(((size_t)(b * 16 + h)) * 2048 + s) * 64 + d] = (__bf16)o;
            else
              Ok[(((size_t)(b * 16 + h)) * 2048 + s) * 64 + d] = (__bf16)o;
          } else {
            Ov[(((size_t)(b * 16 + h)) * 64 + d) * 2048 + s] = (__bf16)v;  // transposed
          }
        } else {
          Of[(size_t)mg * 1024 + col] = v;
        }
      }
}

// ---------------------------------------------------------------------------
// Flash attention, causal, swapped-QK^T structure (32x32x16 MFMA).
// Grid: bid = qti*64 + bh; qt = 7-qti (heavy first). Block: 512 thr (8 waves),
// wave owns 32 q-rows (block q-tile = 256). KVBLK=64 double-buffered in LDS
// (K [64 kv][64 d], V^T [64 d][64 kv], XOR-swizzled, conflict-free).
// mfma(K,Q) => lane holds scores[kv 0..31][q=lane&31] per 32-tile: softmax is
// in-register (31 fmax + 1 shfl). PV via mfma(V^T, P^T) -> out^T[d][q].
// P^T B-frags assembled with 2 shfl_xor(32) per 16-kv band (T12-style).
// ---------------------------------------------------------------------------
__global__ __launch_bounds__(512, 2) void attn_kernel(
    const __bf16* __restrict__ Q, const __bf16* __restrict__ Kb,
    const __bf16* __restrict__ Vt, __bf16* __restrict__ Ob) {
  __shared__ unsigned char sm[32768];  // [K0 8K][V0 8K][K1 8K][V1 8K]
  int bid = blockIdx.x;
  int bh = bid & 63;
  int qt = 7 - (bid >> 6);
  int b = bh >> 4, h = bh & 15;
  const __bf16* Qp = Q + (size_t)bh * 2048 * 64;
  const __bf16* Kp = Kb + (size_t)bh * 2048 * 64;
  const __bf16* Vp = Vt + (size_t)bh * 64 * 2048;
  int t = threadIdx.x;
  int w = t >> 6, lane = t & 63;
  int q31 = lane & 31, hi = lane >> 5;
  int qw = qt * 256 + w * 32;
  int qg = qw + q31;

  // Q as B-operand fragments: k = kk*16 + hi*8 + idx
  bf16x8 qF[4];
#pragma unroll
  for (int kk = 0; kk < 4; ++kk)
    qF[kk] = *(const bf16x8*)(Qp + (size_t)qg * 64 + kk * 16 + hi * 8);

  f32x16 accO[2] = {};  // out^T: accO[dt][rr] -> d=(rr&3)+8*(rr>>2)+4*hi+32*dt, q=q31
  float m = -1e30f, l = 0.f;

  int nsteps = (qt + 1) * 4;
  auto stage = [&](int buf, int step) {
    int kv0 = step * 64;
    int r = t >> 3, sl = t & 7;
    gload_lds16(Kp + (size_t)(kv0 + r) * 64 + ((sl ^ (r & 7)) << 3),
                &sm[(unsigned)buf * 16384u + (unsigned)t * 16]);
    gload_lds16(Vp + (size_t)r * 2048 + kv0 + ((sl ^ (r & 7)) << 3),
                &sm[(unsigned)buf * 16384u + 8192u + (unsigned)t * 16]);
  };

  stage(0, 0);
  __syncthreads();
  int buf = 0;
  for (int step = 0; step < nsteps; ++step) {
    if (step + 1 < nsteps) stage(buf ^ 1, step + 1);
    int kv0 = step * 64;
    if (kv0 <= qw) {  // wave-uniform causal skip
      unsigned koff = (unsigned)buf * 16384u, voff = koff + 8192u;
      f32x16 sc[2] = {};  // sc[tt][rr]: kv = kv0+32*tt+(rr&3)+8*(rr>>2)+4*hi, q=q31
      // ---- QK^T (swapped: A=K, B=Q) ----
#pragma unroll
      for (int tt = 0; tt < 2; ++tt)
#pragma unroll
        for (int kk = 0; kk < 4; ++kk) {
          int row = tt * 32 + q31;
          int chunk = kk * 2 + hi;
          bf16x8 kf = *(const bf16x8*)&sm[koff + (unsigned)(row * 128 + ((chunk ^ (row & 7)) << 4))];
          sc[tt] = __builtin_amdgcn_mfma_f32_32x32x16_bf16(kf, qF[kk], sc[tt], 0, 0, 0);
        }
      // ---- causal mask (only the diagonal-crossing step) ----
      if (kv0 + 64 > qw) {
        int hi4 = hi * 4;
#pragma unroll
        for (int tt = 0; tt < 2; ++tt)
#pragma unroll
          for (int rr = 0; rr < 16; ++rr) {
            int kvg = kv0 + tt * 32 + (rr & 3) + 8 * (rr >> 2) + hi4;
            if (kvg > qg) sc[tt][rr] = -1e30f;
          }
      }
      // ---- online softmax, fully in-register ----
      float mt_ = -1e30f;
#pragma unroll
      for (int tt = 0; tt < 2; ++tt)
#pragma unroll
        for (int rr = 0; rr < 16; ++rr) mt_ = fmaxf(mt_, sc[tt][rr]);
      mt_ = fmaxf(mt_, __shfl_xor(mt_, 32));
      float mnew = fmaxf(m, mt_);
      float alpha = __expf(m - mnew);
      m = mnew;
      float ls = 0.f;
#pragma unroll
      for (int tt = 0; tt < 2; ++tt)
#pragma unroll
        for (int rr = 0; rr < 16; ++rr) {
          float p = __expf(sc[tt][rr] - mnew);
          sc[tt][rr] = p;
          ls += p;
        }
      ls += __shfl_xor(ls, 32);
      l = l * alpha + ls;
#pragma unroll
      for (int dt = 0; dt < 2; ++dt)
#pragma unroll
        for (int rr = 0; rr < 16; ++rr) accO[dt][rr] *= alpha;
      // ---- P^T -> bf16 B-frags + PV (per 32-kv tile) ----
#pragma unroll
      for (int tt = 0; tt < 2; ++tt) {
        unsigned pk[8];
#pragma unroll
        for (int i = 0; i < 8; ++i) pk[i] = pk2(sc[tt][2 * i], sc[tt][2 * i + 1]);
#pragma unroll
        for (int mm = 0; mm < 2; ++mm) {
          int ks = tt * 2 + mm;
          // exchange: hi=0 sends pk[4m+2..3], hi=1 sends pk[4m..4m+1]
          unsigned z0 = hi ? pk[4 * mm] : pk[4 * mm + 2];
          unsigned z1 = hi ? pk[4 * mm + 1] : pk[4 * mm + 3];
          unsigned zx0 = (unsigned)__shfl_xor((int)z0, 32);
          unsigned zx1 = (unsigned)__shfl_xor((int)z1, 32);
          union { unsigned u[4]; bf16x8 v; } pf;
          pf.u[0] = hi ? zx0 : pk[4 * mm];
          pf.u[1] = hi ? zx1 : pk[4 * mm + 1];
          pf.u[2] = hi ? pk[4 * mm + 2] : zx0;
          pf.u[3] = hi ? pk[4 * mm + 3] : zx1;
#pragma unroll
          for (int dt = 0; dt < 2; ++dt) {
            int row = dt * 32 + q31;
            int chunk = ks * 2 + hi;
            bf16x8 vf = *(const bf16x8*)&sm[voff + (unsigned)(row * 128 + ((chunk ^ (row & 7)) << 4))];
            accO[dt] = __builtin_amdgcn_mfma_f32_32x32x16_bf16(vf, pf.v, accO[dt], 0, 0, 0);
          }
        }
      }
    }
    __syncthreads();
    buf ^= 1;
  }
  // ---- epilogue: O = accO^T / l  ->  [b,s,h,d] bf16 ----
  float inv = 1.0f / l;
#pragma unroll
  for (int dt = 0; dt < 2; ++dt)
#pragma unroll
    for (int q4 = 0; q4 < 4; ++q4) {
      int dbase = dt * 32 + hi * 4 + 8 * q4;
      bf16x4 o;
#pragma unroll
      for (int ii = 0; ii < 4; ++ii) o[ii] = (__bf16)(accO[dt][q4 * 4 + ii] * inv);
      *(bf16x4*)(Ob + (((size_t)(b * 2048 + qg)) * 16 + h) * 64 + dbase) = o;
    }
}

// ---------------------------------------------------------------------------
extern "C" void kernel_launch(void* const* d_in, const int* in_sizes, int n_in,
                              void* d_out, int out_size, void* d_ws, size_t ws_size,
                              hipStream_t stream) {
  const float* x  = (const float*)d_in[0];
  const float* wq = (const float*)d_in[1];
  const float* wk = (const float*)d_in[2];
  const float* wv = (const float*)d_in[3];
  const float* wo = (const float*)d_in[4];
  const int* pos  = (const int*)d_in[5];
  float* out = (float*)d_out;

  char* ws = (char*)d_ws;
  size_t off = 0;
  auto alloc = [&](size_t bytes) {
    void* p = ws + off;
    off += (bytes + 255) & ~(size_t)255;
    return p;
  };
  __bf16* xb  = (__bf16*)alloc(16777216);   // [8192][1024]; dead after GEMM<0>
  __bf16* ab  = xb;                          // reuse: attn out [b,s,h,d]
  __bf16* wqb = (__bf16*)alloc(2097152);
  __bf16* wkb = (__bf16*)alloc(2097152);
  __bf16* wvb = (__bf16*)alloc(2097152);
  __bf16* wob = (__bf16*)alloc(2097152);
  __bf16* qb  = (__bf16*)alloc(16777216);   // [b,h,s,64] (rope'd, *0.125)
  __bf16* kb  = (__bf16*)alloc(16777216);   // [b,h,s,64] (rope'd)
  __bf16* vt  = (__bf16*)alloc(16777216);   // [b,h,64,s] (transposed)
  float2* trig = (float2*)alloc(524288);    // [2048][32]

  conv_kernel<<<8192, 256, 0, stream>>>(x, xb, 2097152);
  conv4_kernel<<<4096, 256, 0, stream>>>(wq, wk, wv, wo, wqb, wkb, wvb, wob);
  trig_kernel<<<256, 256, 0, stream>>>(pos, trig);

  gemm_kernel<0><<<1536, 256, 0, stream>>>(xb, wqb, wkb, wvb, qb, kb, vt, nullptr, trig);
  attn_kernel<<<512, 512, 0, stream>>>(qb, kb, vt, ab);
  gemm_kernel<1><<<512, 256, 0, stream>>>(ab, wob, wob, wob, nullptr, nullptr, nullptr, out, nullptr);
}

// Round 4
// 253.866 us; speedup vs baseline: 1.3546x; 1.1769x over previous
//
#include <hip/hip_runtime.h>
#include <hip/hip_bf16.h>
#include <math.h>

// ---------------------------------------------------------------------------
// MultiheadSelfAttentionWithRope on MI355X (gfx950), bf16 MFMA pipeline.
// B=4, S=2048, D=1024, H=16, dk=64.  fp32 accumulate everywhere.
//
// Stages:
//   1. convert x (+4 weights fused) fp32 -> bf16
//   2. trig table cos/sin [2048][32]
//   3. GEMM<0>: QKV projection (N=3072 fused); epilogue applies RoPE to Q,K
//      (Q also *0.125) and scatters Q,K -> [b,h,s,dk]; V -> [b,h,dk,s] via
//      LDS transpose (coalesced 16B stores)
//   4. flash attention (swapped-QK^T, in-register softmax) -> ab [b,s,h,dk]
//   5. GEMM<1>: out = ab @ wo.T -> d_out fp32
//
// Block->XCD partitioning: xcd = bid&7 owns a contiguous 8-mt slab of A
// (2 MB, L2-resident) across all nt. Attn: xcd owns 8 bh (4 MB KV = one L2).
// ---------------------------------------------------------------------------

typedef __bf16 bf16x8 __attribute__((ext_vector_type(8)));
typedef __bf16 bf16x4 __attribute__((ext_vector_type(4)));
typedef float  f32x4  __attribute__((ext_vector_type(4)));
typedef float  f32x16 __attribute__((ext_vector_type(16)));

#define GLB __attribute__((address_space(1)))
#define LDS __attribute__((address_space(3)))

__device__ __forceinline__ void gload_lds16(const void* g, void* l) {
  __builtin_amdgcn_global_load_lds((const GLB unsigned int*)g,
                                   (LDS unsigned int*)l, 16, 0, 0);
}

__device__ __forceinline__ unsigned pk2(float a, float b) {
  __bf16 x = (__bf16)a, y = (__bf16)b;
  unsigned short ux = __builtin_bit_cast(unsigned short, x);
  unsigned short uy = __builtin_bit_cast(unsigned short, y);
  return (unsigned)ux | ((unsigned)uy << 16);
}

// ---------------------------------------------------------------------------
__global__ __launch_bounds__(256) void conv_kernel(const float* __restrict__ in,
                                                   __bf16* __restrict__ out, int n4) {
  int i = blockIdx.x * 256 + threadIdx.x;
  if (i < n4) {
    float4 v = ((const float4*)in)[i];
    bf16x4 o = {(__bf16)v.x, (__bf16)v.y, (__bf16)v.z, (__bf16)v.w};
    ((bf16x4*)out)[i] = o;
  }
}

// 4 weight matrices (each 1M floats) in one launch
__global__ __launch_bounds__(256) void conv4_kernel(
    const float* __restrict__ a, const float* __restrict__ b,
    const float* __restrict__ c, const float* __restrict__ d,
    __bf16* __restrict__ oa, __bf16* __restrict__ ob,
    __bf16* __restrict__ oc, __bf16* __restrict__ od) {
  int i = blockIdx.x * 256 + threadIdx.x;  // 4 * 262144
  int w = i >> 18, j = i & 262143;
  const float* src = w == 0 ? a : (w == 1 ? b : (w == 2 ? c : d));
  __bf16* dst = w == 0 ? oa : (w == 1 ? ob : (w == 2 ? oc : od));
  float4 v = ((const float4*)src)[j];
  bf16x4 o = {(__bf16)v.x, (__bf16)v.y, (__bf16)v.z, (__bf16)v.w};
  ((bf16x4*)dst)[j] = o;
}

// ---------------------------------------------------------------------------
__global__ __launch_bounds__(256) void trig_kernel(const int* __restrict__ pos,
                                                   float2* __restrict__ trig) {
  int i = blockIdx.x * 256 + threadIdx.x;  // 65536 total
  int s = i >> 5, fi = i & 31;
  float p = (float)pos[s];
  float freq = expf(-(float)fi * 0.28782313662425574f);  // ln(10000)/32
  float ang = p * freq;
  trig[i] = make_float2(cosf(ang), sinf(ang));
}

// ---------------------------------------------------------------------------
// 2-phase double-buffered bf16 GEMM, 128x128 tile, BK=64, 4 waves.
// LDS tiles [128 rows][64 k], 16B-chunk XOR swizzle via pre-swizzled global src.
// Block map: mt = (bid&7)*8 + (idx&7), nt = idx>>3  (idx = bid>>3).
// MODE 0: N=3072 (wq|wk|wv); RoPE fused for Q,K; V transposed via LDS.
// MODE 1: N=1024 (wo), epilogue writes fp32 d_out.
// ---------------------------------------------------------------------------
template <int MODE>
__global__ __launch_bounds__(256, 2) void gemm_kernel(
    const __bf16* __restrict__ A, const __bf16* __restrict__ Bq,
    const __bf16* __restrict__ Bk, const __bf16* __restrict__ Bv,
    __bf16* __restrict__ Oq, __bf16* __restrict__ Ok, __bf16* __restrict__ Ov,
    float* __restrict__ Of, const float2* __restrict__ trig) {
  __shared__ unsigned char sm[65536];  // [A0 16K][B0 16K][A1 16K][B1 16K]
  int bid = blockIdx.x;
  int xcd = bid & 7, idx = bid >> 3;
  int mt = xcd * 8 + (idx & 7);   // XCD-local 8-tile A slab (2 MB, L2-resident)
  int nt = idx >> 3;
  int m0 = mt * 128;
  const __bf16* Bp;
  int ncol0, sel = 0;
  if (MODE == 0) {
    sel = nt >> 3;
    Bp = sel == 0 ? Bq : (sel == 1 ? Bk : Bv);
    ncol0 = (nt & 7) * 128;
  } else {
    Bp = Bq;
    ncol0 = nt * 128;
  }
  int t = threadIdx.x;
  int lane = t & 63, w = t >> 6;
  int g = lane >> 4, l15 = lane & 15;
  int wm = w >> 1, wn = w & 1;

  auto stage = [&](int buf, int kt) {
    unsigned boff = (unsigned)buf * 32768u;
#pragma unroll
    for (int l = 0; l < 4; ++l) {
      int c = t + l * 256;
      int r = c >> 3, sl = c & 7;
      int gk = kt * 64 + ((sl ^ (r & 7)) << 3);
      gload_lds16(A + (size_t)(m0 + r) * 1024 + gk, &sm[boff + (unsigned)c * 16]);
    }
#pragma unroll
    for (int l = 0; l < 4; ++l) {
      int c = t + l * 256;
      int r = c >> 3, sl = c & 7;
      int gk = kt * 64 + ((sl ^ (r & 7)) << 3);
      gload_lds16(Bp + (size_t)(ncol0 + r) * 1024 + gk,
                  &sm[boff + 16384u + (unsigned)c * 16]);
    }
  };

  f32x4 acc[4][4] = {};
  stage(0, 0);
  __syncthreads();
  int buf = 0;
  for (int kt = 0; kt < 16; ++kt) {
    if (kt + 1 < 16) stage(buf ^ 1, kt + 1);
    unsigned aoff = (unsigned)buf * 32768u, boff2 = aoff + 16384u;
#pragma unroll
    for (int ks = 0; ks < 2; ++ks) {
      bf16x8 aF[4], bF[4];
      int chunk = ks * 4 + g;
#pragma unroll
      for (int mi = 0; mi < 4; ++mi) {
        int r = wm * 64 + mi * 16 + l15;
        aF[mi] = *(const bf16x8*)&sm[aoff + (unsigned)(r * 128 + ((chunk ^ (r & 7)) << 4))];
      }
#pragma unroll
      for (int ni = 0; ni < 4; ++ni) {
        int r = wn * 64 + ni * 16 + l15;
        bF[ni] = *(const bf16x8*)&sm[boff2 + (unsigned)(r * 128 + ((chunk ^ (r & 7)) << 4))];
      }
#pragma unroll
      for (int mi = 0; mi < 4; ++mi)
#pragma unroll
        for (int ni = 0; ni < 4; ++ni)
          acc[mi][ni] = __builtin_amdgcn_mfma_f32_16x16x32_bf16(aF[mi], bF[ni],
                                                                acc[mi][ni], 0, 0, 0);
    }
    __syncthreads();
    buf ^= 1;
  }
  // ---- epilogue: C row = (lane>>4)*4+j, col = lane&15 ----
  if (MODE == 0 && sel == 2) {
    // V: transpose the 128x128 tile through LDS, store [b,h,d,s] coalesced.
    // LDS layout: byte = col*256 + ((row>>3 ^ (col&15))<<4) + (row&7)*2
#pragma unroll
    for (int mi = 0; mi < 4; ++mi)
#pragma unroll
      for (int ni = 0; ni < 4; ++ni)
#pragma unroll
        for (int j = 0; j < 4; ++j) {
          int row = wm * 64 + mi * 16 + g * 4 + j;
          int col = wn * 64 + ni * 16 + l15;
          unsigned byte = (unsigned)(col * 256 + ((((row >> 3) ^ (col & 15))) << 4) + ((row & 7) << 1));
          *(__bf16*)&sm[byte] = (__bf16)acc[mi][ni][j];
        }
    __syncthreads();
    int b = m0 >> 11, s0 = m0 & 2047;
#pragma unroll
    for (int i = 0; i < 8; ++i) {
      int c = t + i * 256;     // 0..2047
      int dcol = c >> 4;       // col_local 0..127
      int sc = c & 15;         // 8-s chunk
      bf16x8 v = *(const bf16x8*)&sm[(unsigned)(dcol * 256 + ((sc ^ (dcol & 15)) << 4))];
      int colg = ncol0 + dcol;
      int h = colg >> 6, d = colg & 63;
      *(bf16x8*)(Ov + (((size_t)(b * 16 + h)) * 64 + d) * 2048 + s0 + sc * 8) = v;
    }
  } else {
#pragma unroll
    for (int mi = 0; mi < 4; ++mi)
#pragma unroll
      for (int ni = 0; ni < 4; ++ni)
#pragma unroll
        for (int j = 0; j < 4; ++j) {
          int mg = m0 + wm * 64 + mi * 16 + g * 4 + j;
          int col = ncol0 + wn * 64 + ni * 16 + l15;
          float v = acc[mi][ni][j];
          if (MODE == 0) {
            int h = col >> 6, d = col & 63;
            int b = mg >> 11, s = mg & 2047;
            // fused RoPE: partner lane holds the other half of the (even,odd) pair
            float p = __shfl_xor(v, 1);
            float2 cs = trig[s * 32 + (d >> 1)];
            float o = (d & 1) ? (p * cs.y + v * cs.x) : (v * cs.x - p * cs.y);
            if (sel == 0) {
              o *= 0.125f;  // 1/sqrt(dk) folded into Q
              Oq[(((size_t)(b * 16 + h)) * 2048 + s) * 64 + d] = (__bf16)o;
            } else {
              Ok[(((size_t)(b * 16 + h)) * 2048 + s) * 64 + d] = (__bf16)o;
            }
          } else {
            Of[(size_t)mg * 1024 + col] = v;
          }
        }
  }
}

// ---------------------------------------------------------------------------
// Flash attention, causal, swapped-QK^T structure (32x32x16 MFMA).
// bid map: bh = (bid&7)*8 + ((bid>>3)&7)  -> each XCD owns 8 bh (4 MB KV, L2);
// qt = 7 - (bid>>6), heavy tiles dispatched first. Block: 512 thr (8 waves),
// wave owns 32 q-rows. KVBLK=64 double-buffered in LDS (K [64 kv][64 d],
// V^T [64 d][64 kv], XOR-swizzled). mfma(K,Q): lane = one q-row, in-register
// softmax (31 fmax + 1 shfl). PV via mfma(V^T, P^T) -> out^T[d][q].
// ---------------------------------------------------------------------------
__global__ __launch_bounds__(512, 2) void attn_kernel(
    const __bf16* __restrict__ Q, const __bf16* __restrict__ Kb,
    const __bf16* __restrict__ Vt, __bf16* __restrict__ Ob) {
  __shared__ unsigned char sm[32768];  // [K0 8K][V0 8K][K1 8K][V1 8K]
  int bid = blockIdx.x;
  int bh = (bid & 7) * 8 + ((bid >> 3) & 7);
  int qt = 7 - (bid >> 6);
  int b = bh >> 4, h = bh & 15;
  const __bf16* Qp = Q + (size_t)bh * 2048 * 64;
  const __bf16* Kp = Kb + (size_t)bh * 2048 * 64;
  const __bf16* Vp = Vt + (size_t)bh * 64 * 2048;
  int t = threadIdx.x;
  int w = t >> 6, lane = t & 63;
  int q31 = lane & 31, hi = lane >> 5;
  int qw = qt * 256 + w * 32;
  int qg = qw + q31;

  // Q as B-operand fragments: k = kk*16 + hi*8 + idx
  bf16x8 qF[4];
#pragma unroll
  for (int kk = 0; kk < 4; ++kk)
    qF[kk] = *(const bf16x8*)(Qp + (size_t)qg * 64 + kk * 16 + hi * 8);

  f32x16 accO[2] = {};  // out^T: accO[dt][rr] -> d=(rr&3)+8*(rr>>2)+4*hi+32*dt, q=q31
  float m = -1e30f, l = 0.f;

  int nsteps = (qt + 1) * 4;
  auto stage = [&](int buf, int step) {
    int kv0 = step * 64;
    int r = t >> 3, sl = t & 7;
    gload_lds16(Kp + (size_t)(kv0 + r) * 64 + ((sl ^ (r & 7)) << 3),
                &sm[(unsigned)buf * 16384u + (unsigned)t * 16]);
    gload_lds16(Vp + (size_t)r * 2048 + kv0 + ((sl ^ (r & 7)) << 3),
                &sm[(unsigned)buf * 16384u + 8192u + (unsigned)t * 16]);
  };

  stage(0, 0);
  __syncthreads();
  int buf = 0;
  for (int step = 0; step < nsteps; ++step) {
    if (step + 1 < nsteps) stage(buf ^ 1, step + 1);
    int kv0 = step * 64;
    if (kv0 <= qw) {  // wave-uniform causal skip
      unsigned koff = (unsigned)buf * 16384u, voff = koff + 8192u;
      f32x16 sc[2] = {};  // sc[tt][rr]: kv = kv0+32*tt+(rr&3)+8*(rr>>2)+4*hi, q=q31
      // ---- QK^T (swapped: A=K, B=Q) ----
      __builtin_amdgcn_s_setprio(1);
#pragma unroll
      for (int tt = 0; tt < 2; ++tt)
#pragma unroll
        for (int kk = 0; kk < 4; ++kk) {
          int row = tt * 32 + q31;
          int chunk = kk * 2 + hi;
          bf16x8 kf = *(const bf16x8*)&sm[koff + (unsigned)(row * 128 + ((chunk ^ (row & 7)) << 4))];
          sc[tt] = __builtin_amdgcn_mfma_f32_32x32x16_bf16(kf, qF[kk], sc[tt], 0, 0, 0);
        }
      __builtin_amdgcn_s_setprio(0);
      // ---- causal mask (only the diagonal-crossing step) ----
      if (kv0 + 64 > qw) {
        int hi4 = hi * 4;
#pragma unroll
        for (int tt = 0; tt < 2; ++tt)
#pragma unroll
          for (int rr = 0; rr < 16; ++rr) {
            int kvg = kv0 + tt * 32 + (rr & 3) + 8 * (rr >> 2) + hi4;
            if (kvg > qg) sc[tt][rr] = -1e30f;
          }
      }
      // ---- online softmax, fully in-register ----
      float mt_ = -1e30f;
#pragma unroll
      for (int tt = 0; tt < 2; ++tt)
#pragma unroll
        for (int rr = 0; rr < 16; ++rr) mt_ = fmaxf(mt_, sc[tt][rr]);
      mt_ = fmaxf(mt_, __shfl_xor(mt_, 32));
      float mnew = fmaxf(m, mt_);
      float alpha = __expf(m - mnew);
      m = mnew;
      float ls = 0.f;
#pragma unroll
      for (int tt = 0; tt < 2; ++tt)
#pragma unroll
        for (int rr = 0; rr < 16; ++rr) {
          float p = __expf(sc[tt][rr] - mnew);
          sc[tt][rr] = p;
          ls += p;
        }
      ls += __shfl_xor(ls, 32);
      l = l * alpha + ls;
#pragma unroll
      for (int dt = 0; dt < 2; ++dt)
#pragma unroll
        for (int rr = 0; rr < 16; ++rr) accO[dt][rr] *= alpha;
      // ---- P^T -> bf16 B-frags + PV (per 32-kv tile) ----
#pragma unroll
      for (int tt = 0; tt < 2; ++tt) {
        unsigned pk[8];
#pragma unroll
        for (int i = 0; i < 8; ++i) pk[i] = pk2(sc[tt][2 * i], sc[tt][2 * i + 1]);
#pragma unroll
        for (int mm = 0; mm < 2; ++mm) {
          int ks = tt * 2 + mm;
          // exchange: hi=0 sends pk[4m+2..3], hi=1 sends pk[4m..4m+1]
          unsigned z0 = hi ? pk[4 * mm] : pk[4 * mm + 2];
          unsigned z1 = hi ? pk[4 * mm + 1] : pk[4 * mm + 3];
          unsigned zx0 = (unsigned)__shfl_xor((int)z0, 32);
          unsigned zx1 = (unsigned)__shfl_xor((int)z1, 32);
          union { unsigned u[4]; bf16x8 v; } pf;
          pf.u[0] = hi ? zx0 : pk[4 * mm];
          pf.u[1] = hi ? zx1 : pk[4 * mm + 1];
          pf.u[2] = hi ? pk[4 * mm + 2] : zx0;
          pf.u[3] = hi ? pk[4 * mm + 3] : zx1;
          __builtin_amdgcn_s_setprio(1);
#pragma unroll
          for (int dt = 0; dt < 2; ++dt) {
            int row = dt * 32 + q31;
            int chunk = ks * 2 + hi;
            bf16x8 vf = *(const bf16x8*)&sm[voff + (unsigned)(row * 128 + ((chunk ^ (row & 7)) << 4))];
            accO[dt] = __builtin_amdgcn_mfma_f32_32x32x16_bf16(vf, pf.v, accO[dt], 0, 0, 0);
          }
          __builtin_amdgcn_s_setprio(0);
        }
      }
    }
    __syncthreads();
    buf ^= 1;
  }
  // ---- epilogue: O = accO^T / l  ->  [b,s,h,d] bf16 ----
  float inv = 1.0f / l;
#pragma unroll
  for (int dt = 0; dt < 2; ++dt)
#pragma unroll
    for (int q4 = 0; q4 < 4; ++q4) {
      int dbase = dt * 32 + hi * 4 + 8 * q4;
      bf16x4 o;
#pragma unroll
      for (int ii = 0; ii < 4; ++ii) o[ii] = (__bf16)(accO[dt][q4 * 4 + ii] * inv);
      *(bf16x4*)(Ob + (((size_t)(b * 2048 + qg)) * 16 + h) * 64 + dbase) = o;
    }
}

// ---------------------------------------------------------------------------
extern "C" void kernel_launch(void* const* d_in, const int* in_sizes, int n_in,
                              void* d_out, int out_size, void* d_ws, size_t ws_size,
                              hipStream_t stream) {
  const float* x  = (const float*)d_in[0];
  const float* wq = (const float*)d_in[1];
  const float* wk = (const float*)d_in[2];
  const float* wv = (const float*)d_in[3];
  const float* wo = (const float*)d_in[4];
  const int* pos  = (const int*)d_in[5];
  float* out = (float*)d_out;

  char* ws = (char*)d_ws;
  size_t off = 0;
  auto alloc = [&](size_t bytes) {
    void* p = ws + off;
    off += (bytes + 255) & ~(size_t)255;
    return p;
  };
  __bf16* xb  = (__bf16*)alloc(16777216);   // [8192][1024]; dead after GEMM<0>
  __bf16* ab  = xb;                          // reuse: attn out [b,s,h,d]
  __bf16* wqb = (__bf16*)alloc(2097152);
  __bf16* wkb = (__bf16*)alloc(2097152);
  __bf16* wvb = (__bf16*)alloc(2097152);
  __bf16* wob = (__bf16*)alloc(2097152);
  __bf16* qb  = (__bf16*)alloc(16777216);   // [b,h,s,64] (rope'd, *0.125)
  __bf16* kb  = (__bf16*)alloc(16777216);   // [b,h,s,64] (rope'd)
  __bf16* vt  = (__bf16*)alloc(16777216);   // [b,h,64,s] (transposed)
  float2* trig = (float2*)alloc(524288);    // [2048][32]

  conv_kernel<<<8192, 256, 0, stream>>>(x, xb, 2097152);
  conv4_kernel<<<4096, 256, 0, stream>>>(wq, wk, wv, wo, wqb, wkb, wvb, wob);
  trig_kernel<<<256, 256, 0, stream>>>(pos, trig);

  gemm_kernel<0><<<1536, 256, 0, stream>>>(xb, wqb, wkb, wvb, qb, kb, vt, nullptr, trig);
  attn_kernel<<<512, 512, 0, stream>>>(qb, kb, vt, ab);
  gemm_kernel<1><<<512, 256, 0, stream>>>(ab, wob, wob, wob, nullptr, nullptr, nullptr, out, nullptr);
}